// Round 1
// baseline (1110.985 us; speedup 1.0000x reference)
//
#include <hip/hip_runtime.h>
#include <stdint.h>
#include <stddef.h>

typedef __attribute__((ext_vector_type(8))) short short8;
typedef __attribute__((ext_vector_type(4))) float floatx4;

#define T_TOK 16384
#define DM 1024
#define DF 4096
#define NE 8
#define CAP 2048

// fp32 -> bf16 round-to-nearest-even
static __device__ __forceinline__ unsigned short f2bf(float f) {
  union { float f; unsigned u; } v; v.f = f;
  unsigned u = v.u;
  return (unsigned short)((u + 0x7fffu + ((u >> 16) & 1u)) >> 16);
}

// async global->LDS, 16 bytes per lane. LDS dest is wave-uniform base + lane*16,
// so per-lane lds ptr must be base + (lane within wave)*16 (we index by tid*16).
static __device__ __forceinline__ void async_cp16(const void* g, void* l) {
  typedef const unsigned int __attribute__((address_space(1)))* gp_t;
  typedef unsigned int __attribute__((address_space(3)))* lp_t;
  __builtin_amdgcn_global_load_lds((gp_t)g, (lp_t)l, 16, 0, 0);
}

// ---------------------------------------------------------------- init
__global__ void init_kernel(int* __restrict__ src_token, float* __restrict__ stats) {
  int i = blockIdx.x * 256 + threadIdx.x;
  if (i < NE * CAP) src_token[i] = -1;
  if (i < 16) stats[i] = 0.f;
}

// ---------------------------------------------------------------- router
// one wave per token (strided); w_router rows cached in registers (lane owns k = lane+64i)
__global__ void __launch_bounds__(256) router_kernel(
    const float* __restrict__ x, const float* __restrict__ wr,
    int* __restrict__ top_idx, float* __restrict__ top_prob,
    float* __restrict__ stats) {
  int tid = threadIdx.x;
  int lane = tid & 63;
  int gw = (blockIdx.x * 256 + tid) >> 6;  // 2048 waves total
  float w[16][8];
#pragma unroll
  for (int i = 0; i < 16; i++) {
    const float4* p = (const float4*)&wr[(lane + 64 * i) * 8];
    float4 a = p[0], b = p[1];
    w[i][0] = a.x; w[i][1] = a.y; w[i][2] = a.z; w[i][3] = a.w;
    w[i][4] = b.x; w[i][5] = b.y; w[i][6] = b.z; w[i][7] = b.w;
  }
  float pi_acc[8] = {0, 0, 0, 0, 0, 0, 0, 0};
  float z_acc = 0.f;
  for (int t = gw; t < T_TOK; t += 2048) {
    const float* xr = &x[(size_t)t * DM];
    float acc[8] = {0, 0, 0, 0, 0, 0, 0, 0};
#pragma unroll
    for (int i = 0; i < 16; i++) {
      float xv = xr[lane + 64 * i];
#pragma unroll
      for (int e = 0; e < 8; e++) acc[e] = fmaf(xv, w[i][e], acc[e]);
    }
#pragma unroll
    for (int off = 32; off > 0; off >>= 1) {
#pragma unroll
      for (int e = 0; e < 8; e++) acc[e] += __shfl_xor(acc[e], off, 64);
    }
    float mx = acc[0]; int mi = 0;
#pragma unroll
    for (int e = 1; e < 8; e++) { if (acc[e] > mx) { mx = acc[e]; mi = e; } }
    float s = 0.f, pr[8];
#pragma unroll
    for (int e = 0; e < 8; e++) { pr[e] = __expf(acc[e] - mx); s += pr[e]; }
    float inv = 1.f / s;
#pragma unroll
    for (int e = 0; e < 8; e++) pi_acc[e] += pr[e] * inv;
    float lse = mx + __logf(s);
    z_acc += lse * lse;
    if (lane == 0) { top_idx[t] = mi; top_prob[t] = pr[mi] * inv; }
  }
  if (lane == 0) {
#pragma unroll
    for (int e = 0; e < 8; e++) atomicAdd(&stats[e], pi_acc[e]);
    atomicAdd(&stats[8], z_acc);
  }
}

// ---------------------------------------------------------------- FCFS scan
// single block, 1024 threads x 16 tokens each; Hillis-Steele over per-chunk counts
__global__ void __launch_bounds__(1024) scan_kernel(
    const int* __restrict__ top_idx, const float* __restrict__ stats,
    int* __restrict__ dest_slot, int* __restrict__ src_token,
    float* __restrict__ aux_out) {
  __shared__ int cnt[1024 * 9];  // stride 9 to dodge bank conflicts
  int tid = threadIdx.x;
  int eloc[16];
  int c[8] = {0, 0, 0, 0, 0, 0, 0, 0};
#pragma unroll
  for (int i = 0; i < 16; i++) {
    int e = top_idx[tid * 16 + i];
    eloc[i] = e;
    c[e]++;
  }
#pragma unroll
  for (int e = 0; e < 8; e++) cnt[tid * 9 + e] = c[e];
  __syncthreads();
  for (int s = 1; s < 1024; s <<= 1) {
    int v[8];
    if (tid >= s) {
#pragma unroll
      for (int e = 0; e < 8; e++) v[e] = cnt[(tid - s) * 9 + e];
    }
    __syncthreads();
    if (tid >= s) {
#pragma unroll
      for (int e = 0; e < 8; e++) cnt[tid * 9 + e] += v[e];
    }
    __syncthreads();
  }
  int run[8];
#pragma unroll
  for (int e = 0; e < 8; e++) run[e] = cnt[tid * 9 + e] - c[e];  // exclusive base
#pragma unroll
  for (int i = 0; i < 16; i++) {
    int t = tid * 16 + i;
    int e = eloc[i];
    int pos = run[e]++;
    int d = (pos < CAP) ? (e * CAP + pos) : -1;
    dest_slot[t] = d;
    if (d >= 0) src_token[d] = t;
  }
  if (tid == 1023) {
    float aux = 0.f;
    for (int e = 0; e < 8; e++)
      aux += ((float)cnt[1023 * 9 + e] / (float)T_TOK) * (stats[e] / (float)T_TOK);
    aux = 0.01f * 8.f * aux + 0.001f * (stats[8] / (float)T_TOK);
    *aux_out = aux;
  }
}

// ---------------------------------------------------------------- dispatch + cast
__global__ void __launch_bounds__(256) dispatch_kernel(
    const float* __restrict__ x, const int* __restrict__ src_token,
    unsigned short* __restrict__ A) {
  int slot = blockIdx.x;
  int tid = threadIdx.x;
  int src = src_token[slot];
  ushort4 v = {0, 0, 0, 0};
  if (src >= 0) {
    float4 xv = *(const float4*)&x[(size_t)src * DM + tid * 4];
    v.x = f2bf(xv.x); v.y = f2bf(xv.y); v.z = f2bf(xv.z); v.w = f2bf(xv.w);
  }
  *(ushort4*)&A[(size_t)slot * DM + tid * 4] = v;
}

// ---------------------------------------------------------------- transpose + cast
// src fp32 [E][K][N] -> dst bf16 [E][N][K]
__global__ void __launch_bounds__(256) transpose_cast_kernel(
    const float* __restrict__ src, unsigned short* __restrict__ dst,
    int K, int N) {
  __shared__ float tile[64][65];
  int e = blockIdx.z;
  int n0 = blockIdx.x * 64, k0 = blockIdx.y * 64;
  int tx = threadIdx.x & 63, ty = threadIdx.x >> 6;
  const float* S = src + (size_t)e * K * N;
  unsigned short* D = dst + (size_t)e * N * K;
#pragma unroll
  for (int r = 0; r < 16; r++) {
    int k = ty + r * 4;
    tile[k][tx] = S[(size_t)(k0 + k) * N + n0 + tx];
  }
  __syncthreads();
#pragma unroll
  for (int r = 0; r < 16; r++) {
    int n = ty + r * 4;
    D[(size_t)(n0 + n) * K + k0 + tx] = f2bf(tile[tx][n]);
  }
}

// ---------------------------------------------------------------- GEMM1: H = relu(A @ w1 + b1), bf16 out
// A [E][CAP][DM] bf16 row-major, BT=W1T [E][DF][DM] bf16 row-major
__global__ void __launch_bounds__(256) gemm1_kernel(
    const unsigned short* __restrict__ A, const unsigned short* __restrict__ BT,
    const float* __restrict__ b1, unsigned short* __restrict__ H) {
  __shared__ unsigned short As[128 * 32];
  __shared__ unsigned short Bs[128 * 32];
  int e = blockIdx.z;
  int n0 = blockIdx.x * 128, m0 = blockIdx.y * 128;
  const unsigned short* Ae = A + (size_t)e * CAP * DM;
  const unsigned short* Be = BT + (size_t)e * DF * DM;
  int tid = threadIdx.x;
  int lane = tid & 63, wid = tid >> 6;
  int wm = (wid & 1) * 64, wn = (wid >> 1) * 64;
  int l15 = lane & 15, q = lane >> 4;
  floatx4 acc[4][4];
#pragma unroll
  for (int i = 0; i < 4; i++)
#pragma unroll
    for (int j = 0; j < 4; j++) acc[i][j] = (floatx4){0.f, 0.f, 0.f, 0.f};
  int c0 = tid, c1 = tid + 256;
  int ar0 = c0 >> 2, ak0 = (c0 & 3) * 8;
  int ar1 = c1 >> 2, ak1 = (c1 & 3) * 8;
  for (int kb = 0; kb < DM; kb += 32) {
    async_cp16(Ae + (size_t)(m0 + ar0) * DM + kb + ak0, (char*)As + c0 * 16);
    async_cp16(Ae + (size_t)(m0 + ar1) * DM + kb + ak1, (char*)As + c1 * 16);
    async_cp16(Be + (size_t)(n0 + ar0) * DM + kb + ak0, (char*)Bs + c0 * 16);
    async_cp16(Be + (size_t)(n0 + ar1) * DM + kb + ak1, (char*)Bs + c1 * 16);
    __syncthreads();
    short8 af[4], bf[4];
#pragma unroll
    for (int i = 0; i < 4; i++)
      af[i] = *(const short8*)&As[(wm + i * 16 + l15) * 32 + q * 8];
#pragma unroll
    for (int j = 0; j < 4; j++)
      bf[j] = *(const short8*)&Bs[(wn + j * 16 + l15) * 32 + q * 8];
#pragma unroll
    for (int i = 0; i < 4; i++)
#pragma unroll
      for (int j = 0; j < 4; j++)
        acc[i][j] = __builtin_amdgcn_mfma_f32_16x16x32_bf16(bf[j], af[i], acc[i][j], 0, 0, 0);
    __syncthreads();
  }
  // D^T layout: m = l15, n = q*4 + reg (4 consecutive n per lane)
  const float* b1e = b1 + e * DF;
#pragma unroll
  for (int i = 0; i < 4; i++) {
    int m = m0 + wm + i * 16 + l15;
#pragma unroll
    for (int j = 0; j < 4; j++) {
      int nb = n0 + wn + j * 16 + q * 4;
      float4 bv = *(const float4*)&b1e[nb];
      floatx4 a = acc[i][j];
      ushort4 hv;
      hv.x = f2bf(fmaxf(a[0] + bv.x, 0.f));
      hv.y = f2bf(fmaxf(a[1] + bv.y, 0.f));
      hv.z = f2bf(fmaxf(a[2] + bv.z, 0.f));
      hv.w = f2bf(fmaxf(a[3] + bv.w, 0.f));
      *(ushort4*)&H[((size_t)e * CAP + m) * DF + nb] = hv;
    }
  }
}

// ---------------------------------------------------------------- GEMM2: out[t] = p*(H @ w2 + b2), scattered
// Hm [E][CAP][DF] bf16, BT=W2T [E][DM][DF] bf16
__global__ void __launch_bounds__(256) gemm2_kernel(
    const unsigned short* __restrict__ Hm, const unsigned short* __restrict__ BT,
    const float* __restrict__ b2, const int* __restrict__ src_token,
    const float* __restrict__ top_prob, float* __restrict__ out) {
  __shared__ unsigned short As[128 * 32];
  __shared__ unsigned short Bs[128 * 32];
  int e = blockIdx.z;
  int n0 = blockIdx.x * 128, m0 = blockIdx.y * 128;
  const unsigned short* Ae = Hm + (size_t)e * CAP * DF;
  const unsigned short* Be = BT + (size_t)e * DM * DF;
  int tid = threadIdx.x;
  int lane = tid & 63, wid = tid >> 6;
  int wm = (wid & 1) * 64, wn = (wid >> 1) * 64;
  int l15 = lane & 15, q = lane >> 4;
  floatx4 acc[4][4];
#pragma unroll
  for (int i = 0; i < 4; i++)
#pragma unroll
    for (int j = 0; j < 4; j++) acc[i][j] = (floatx4){0.f, 0.f, 0.f, 0.f};
  int c0 = tid, c1 = tid + 256;
  int ar0 = c0 >> 2, ak0 = (c0 & 3) * 8;
  int ar1 = c1 >> 2, ak1 = (c1 & 3) * 8;
  for (int kb = 0; kb < DF; kb += 32) {
    async_cp16(Ae + (size_t)(m0 + ar0) * DF + kb + ak0, (char*)As + c0 * 16);
    async_cp16(Ae + (size_t)(m0 + ar1) * DF + kb + ak1, (char*)As + c1 * 16);
    async_cp16(Be + (size_t)(n0 + ar0) * DF + kb + ak0, (char*)Bs + c0 * 16);
    async_cp16(Be + (size_t)(n0 + ar1) * DF + kb + ak1, (char*)Bs + c1 * 16);
    __syncthreads();
    short8 af[4], bf[4];
#pragma unroll
    for (int i = 0; i < 4; i++)
      af[i] = *(const short8*)&As[(wm + i * 16 + l15) * 32 + q * 8];
#pragma unroll
    for (int j = 0; j < 4; j++)
      bf[j] = *(const short8*)&Bs[(wn + j * 16 + l15) * 32 + q * 8];
#pragma unroll
    for (int i = 0; i < 4; i++)
#pragma unroll
      for (int j = 0; j < 4; j++)
        acc[i][j] = __builtin_amdgcn_mfma_f32_16x16x32_bf16(bf[j], af[i], acc[i][j], 0, 0, 0);
    __syncthreads();
  }
  const float* b2e = b2 + e * DM;
#pragma unroll
  for (int i = 0; i < 4; i++) {
    int m = m0 + wm + i * 16 + l15;
    int t = src_token[e * CAP + m];
    if (t < 0) continue;  // unfilled slot: no token gathers it
    float p = top_prob[t];
    float* orow = out + (size_t)t * DM;
#pragma unroll
    for (int j = 0; j < 4; j++) {
      int nb = n0 + wn + j * 16 + q * 4;
      float4 bv = *(const float4*)&b2e[nb];
      floatx4 a = acc[i][j];
      float4 o;
      o.x = p * (a[0] + bv.x);
      o.y = p * (a[1] + bv.y);
      o.z = p * (a[2] + bv.z);
      o.w = p * (a[3] + bv.w);
      *(float4*)&orow[nb] = o;
    }
  }
}

// ---------------------------------------------------------------- dropped-token passthrough
__global__ void __launch_bounds__(256) passthru_kernel(
    const float* __restrict__ x, const int* __restrict__ dest_slot,
    float* __restrict__ out) {
  int t = blockIdx.x;
  if (dest_slot[t] >= 0) return;
  int c = threadIdx.x * 4;
  *(float4*)&out[(size_t)t * DM + c] = *(const float4*)&x[(size_t)t * DM + c];
}

// ---------------------------------------------------------------- launch
extern "C" void kernel_launch(void* const* d_in, const int* in_sizes, int n_in,
                              void* d_out, int out_size, void* d_ws, size_t ws_size,
                              hipStream_t stream) {
  const float* x  = (const float*)d_in[0];
  const float* wr = (const float*)d_in[1];
  const float* w1 = (const float*)d_in[2];
  const float* b1 = (const float*)d_in[3];
  const float* w2 = (const float*)d_in[4];
  const float* b2 = (const float*)d_in[5];
  float* out = (float*)d_out;

  // workspace layout (bytes)
  const size_t OFF_A    = 0;            // 33,554,432  A bf16 [E*CAP, DM]
  const size_t OFF_W1T  = 33554432;     // 67,108,864  W1T bf16 [E][DF][DM]
  const size_t OFF_W2T  = 100663296;    // 67,108,864  W2T bf16 [E][DM][DF]
  const size_t OFF_H    = 167772160;    // 134,217,728 H bf16 [E][CAP][DF]
  const size_t OFF_TIDX = 301989888;    // 65,536
  const size_t OFF_TPRB = 302055424;    // 65,536
  const size_t OFF_DEST = 302120960;    // 65,536
  const size_t OFF_SRC  = 302186496;    // 65,536
  const size_t OFF_STAT = 302252032;    // 64
  if (ws_size < OFF_STAT + 64) return;  // insufficient workspace

  char* ws = (char*)d_ws;
  unsigned short* A_bf = (unsigned short*)(ws + OFF_A);
  unsigned short* W1T  = (unsigned short*)(ws + OFF_W1T);
  unsigned short* W2T  = (unsigned short*)(ws + OFF_W2T);
  unsigned short* Hbuf = (unsigned short*)(ws + OFF_H);
  int*   top_idx   = (int*)(ws + OFF_TIDX);
  float* top_prob  = (float*)(ws + OFF_TPRB);
  int*   dest_slot = (int*)(ws + OFF_DEST);
  int*   src_token = (int*)(ws + OFF_SRC);
  float* stats     = (float*)(ws + OFF_STAT);

  hipLaunchKernelGGL(init_kernel, dim3(64), dim3(256), 0, stream, src_token, stats);
  hipLaunchKernelGGL(router_kernel, dim3(512), dim3(256), 0, stream,
                     x, wr, top_idx, top_prob, stats);
  hipLaunchKernelGGL(scan_kernel, dim3(1), dim3(1024), 0, stream,
                     top_idx, stats, dest_slot, src_token, out + (size_t)T_TOK * DM);
  hipLaunchKernelGGL(dispatch_kernel, dim3(NE * CAP), dim3(256), 0, stream,
                     x, src_token, A_bf);
  hipLaunchKernelGGL(transpose_cast_kernel, dim3(DF / 64, DM / 64, NE), dim3(256), 0, stream,
                     w1, W1T, DM, DF);
  hipLaunchKernelGGL(transpose_cast_kernel, dim3(DM / 64, DF / 64, NE), dim3(256), 0, stream,
                     w2, W2T, DF, DM);
  hipLaunchKernelGGL(gemm1_kernel, dim3(DF / 128, CAP / 128, NE), dim3(256), 0, stream,
                     A_bf, W1T, b1, Hbuf);
  hipLaunchKernelGGL(gemm2_kernel, dim3(DM / 128, CAP / 128, NE), dim3(256), 0, stream,
                     Hbuf, W2T, b2, src_token, top_prob, out);
  hipLaunchKernelGGL(passthru_kernel, dim3(T_TOK), dim3(256), 0, stream,
                     x, dest_slot, out);
}

// Round 2
// 837.409 us; speedup vs baseline: 1.3267x; 1.3267x over previous
//
#include <hip/hip_runtime.h>
#include <stdint.h>
#include <stddef.h>

typedef __attribute__((ext_vector_type(4))) float floatx4;
typedef __attribute__((ext_vector_type(8))) int intx8;

#define T_TOK 16384
#define DM 1024
#define DF 4096
#define NE 8
#define CAP 2048

#define SCALE_ONE 127   // E8M0: 2^0
#define SCALE_W   121   // E8M0: 2^-6 (weights stored pre-scaled by 64)

// pack 4 fp32 -> 4 fp8 e4m3 (OCP) bytes in an int
static __device__ __forceinline__ int pk4(float a, float b, float c, float d) {
  int v = __builtin_amdgcn_cvt_pk_fp8_f32(a, b, 0, false);
  v = __builtin_amdgcn_cvt_pk_fp8_f32(c, d, v, true);
  return v;
}

// async global->LDS, 16 bytes per lane; LDS dest must be wave-uniform base + lane*16
static __device__ __forceinline__ void async_cp16(const void* g, void* l) {
  typedef const unsigned int __attribute__((address_space(1)))* gp_t;
  typedef unsigned int __attribute__((address_space(3)))* lp_t;
  __builtin_amdgcn_global_load_lds((gp_t)g, (lp_t)l, 16, 0, 0);
}

// ---------------------------------------------------------------- init
__global__ void init_kernel(int* __restrict__ src_token, float* __restrict__ stats) {
  int i = blockIdx.x * 256 + threadIdx.x;
  if (i < NE * CAP) src_token[i] = -1;
  if (i < 16) stats[i] = 0.f;
}

// ---------------------------------------------------------------- router (fp32, exact)
__global__ void __launch_bounds__(256) router_kernel(
    const float* __restrict__ x, const float* __restrict__ wr,
    int* __restrict__ top_idx, float* __restrict__ top_prob,
    float* __restrict__ stats) {
  int tid = threadIdx.x;
  int lane = tid & 63;
  int gw = (blockIdx.x * 256 + tid) >> 6;  // 2048 waves total
  float w[16][8];
#pragma unroll
  for (int i = 0; i < 16; i++) {
    const float4* p = (const float4*)&wr[(lane + 64 * i) * 8];
    float4 a = p[0], b = p[1];
    w[i][0] = a.x; w[i][1] = a.y; w[i][2] = a.z; w[i][3] = a.w;
    w[i][4] = b.x; w[i][5] = b.y; w[i][6] = b.z; w[i][7] = b.w;
  }
  float pi_acc[8] = {0, 0, 0, 0, 0, 0, 0, 0};
  float z_acc = 0.f;
  for (int t = gw; t < T_TOK; t += 2048) {
    const float* xr = &x[(size_t)t * DM];
    float acc[8] = {0, 0, 0, 0, 0, 0, 0, 0};
#pragma unroll
    for (int i = 0; i < 16; i++) {
      float xv = xr[lane + 64 * i];
#pragma unroll
      for (int e = 0; e < 8; e++) acc[e] = fmaf(xv, w[i][e], acc[e]);
    }
#pragma unroll
    for (int off = 32; off > 0; off >>= 1) {
#pragma unroll
      for (int e = 0; e < 8; e++) acc[e] += __shfl_xor(acc[e], off, 64);
    }
    float mx = acc[0]; int mi = 0;
#pragma unroll
    for (int e = 1; e < 8; e++) { if (acc[e] > mx) { mx = acc[e]; mi = e; } }
    float s = 0.f, pr[8];
#pragma unroll
    for (int e = 0; e < 8; e++) { pr[e] = __expf(acc[e] - mx); s += pr[e]; }
    float inv = 1.f / s;
#pragma unroll
    for (int e = 0; e < 8; e++) pi_acc[e] += pr[e] * inv;
    float lse = mx + __logf(s);
    z_acc += lse * lse;
    if (lane == 0) { top_idx[t] = mi; top_prob[t] = pr[mi] * inv; }
  }
  if (lane == 0) {
#pragma unroll
    for (int e = 0; e < 8; e++) atomicAdd(&stats[e], pi_acc[e]);
    atomicAdd(&stats[8], z_acc);
  }
}

// ---------------------------------------------------------------- FCFS scan
__global__ void __launch_bounds__(1024) scan_kernel(
    const int* __restrict__ top_idx, const float* __restrict__ stats,
    int* __restrict__ dest_slot, int* __restrict__ src_token,
    float* __restrict__ aux_out) {
  __shared__ int cnt[1024 * 9];
  int tid = threadIdx.x;
  int eloc[16];
  int c[8] = {0, 0, 0, 0, 0, 0, 0, 0};
#pragma unroll
  for (int i = 0; i < 16; i++) {
    int e = top_idx[tid * 16 + i];
    eloc[i] = e;
    c[e]++;
  }
#pragma unroll
  for (int e = 0; e < 8; e++) cnt[tid * 9 + e] = c[e];
  __syncthreads();
  for (int s = 1; s < 1024; s <<= 1) {
    int v[8];
    if (tid >= s) {
#pragma unroll
      for (int e = 0; e < 8; e++) v[e] = cnt[(tid - s) * 9 + e];
    }
    __syncthreads();
    if (tid >= s) {
#pragma unroll
      for (int e = 0; e < 8; e++) cnt[tid * 9 + e] += v[e];
    }
    __syncthreads();
  }
  int run[8];
#pragma unroll
  for (int e = 0; e < 8; e++) run[e] = cnt[tid * 9 + e] - c[e];
#pragma unroll
  for (int i = 0; i < 16; i++) {
    int t = tid * 16 + i;
    int e = eloc[i];
    int pos = run[e]++;
    int d = (pos < CAP) ? (e * CAP + pos) : -1;
    dest_slot[t] = d;
    if (d >= 0) src_token[d] = t;
  }
  if (tid == 1023) {
    float aux = 0.f;
    for (int e = 0; e < 8; e++)
      aux += ((float)cnt[1023 * 9 + e] / (float)T_TOK) * (stats[e] / (float)T_TOK);
    aux = 0.01f * 8.f * aux + 0.001f * (stats[8] / (float)T_TOK);
    *aux_out = aux;
  }
}

// ---------------------------------------------------------------- dispatch + cast fp8
__global__ void __launch_bounds__(256) dispatch_kernel(
    const float* __restrict__ x, const int* __restrict__ src_token,
    unsigned char* __restrict__ A) {
  int slot = blockIdx.x;
  int tid = threadIdx.x;
  int src = src_token[slot];
  int v = 0;
  if (src >= 0) {
    float4 xv = *(const float4*)&x[(size_t)src * DM + tid * 4];
    v = pk4(xv.x, xv.y, xv.z, xv.w);
  }
  *(int*)&A[(size_t)slot * DM + tid * 4] = v;
}

// ---------------------------------------------------------------- transpose + cast fp8 (x64)
// src fp32 [E][K][N] -> dst fp8 [E][N][K], values scaled by 64 (HW scale 2^-6 undoes it)
__global__ void __launch_bounds__(256) transpose_cast_kernel(
    const float* __restrict__ src, unsigned char* __restrict__ dst,
    int K, int N) {
  __shared__ float tile[64][65];
  int e = blockIdx.z;
  int n0 = blockIdx.x * 64, k0 = blockIdx.y * 64;
  int tid = threadIdx.x;
  int tx = tid & 63, ty = tid >> 6;
  const float* S = src + (size_t)e * K * N;
  unsigned char* D = dst + (size_t)e * N * K;
#pragma unroll
  for (int r = 0; r < 16; r++) {
    int k = ty + r * 4;
    tile[k][tx] = S[(size_t)(k0 + k) * N + n0 + tx];
  }
  __syncthreads();
  int n = tid >> 2, kq = (tid & 3) * 16;
  int4 ov;
  int w[4];
#pragma unroll
  for (int g = 0; g < 4; g++) {
    int kk = kq + g * 4;
    w[g] = pk4(tile[kk + 0][n] * 64.f, tile[kk + 1][n] * 64.f,
               tile[kk + 2][n] * 64.f, tile[kk + 3][n] * 64.f);
  }
  ov.x = w[0]; ov.y = w[1]; ov.z = w[2]; ov.w = w[3];
  *(int4*)&D[(size_t)(n0 + n) * K + k0 + kq] = ov;
}

// LDS chunk swizzle: 128-byte rows of 8x16B chunks; data chunk cc stored at cc ^ (row&7)
// -> fragment reads hit 2 lanes/bank (free), staging stays within one 128B segment/row.

// ---------------------------------------------------------------- GEMM1: H = relu(A @ w1 + b1) fp8 out
// A fp8 [E*CAP][DM], BT=W1T fp8x64 [E][DF][DM]
__global__ void __launch_bounds__(256) gemm1_kernel(
    const unsigned char* __restrict__ A, const unsigned char* __restrict__ BT,
    const float* __restrict__ b1, unsigned char* __restrict__ H) {
  __shared__ unsigned char As[128 * 128];
  __shared__ unsigned char Bs[128 * 128];
  int e = blockIdx.z;
  int n0 = blockIdx.x * 128, m0 = blockIdx.y * 128;
  const unsigned char* Ae = A + ((size_t)e * CAP + m0) * DM;
  const unsigned char* Be = BT + ((size_t)e * DF + n0) * DM;
  int tid = threadIdx.x;
  int lane = tid & 63, wid = tid >> 6;
  int wm = (wid & 1) * 64, wn = (wid >> 1) * 64;
  int l15 = lane & 15, q = lane >> 4;
  floatx4 acc[4][4];
#pragma unroll
  for (int i = 0; i < 4; i++)
#pragma unroll
    for (int j = 0; j < 4; j++) acc[i][j] = (floatx4){0.f, 0.f, 0.f, 0.f};
  for (int kb = 0; kb < DM; kb += 128) {
#pragma unroll
    for (int r = 0; r < 4; r++) {
      int c = tid + 256 * r;
      int row = c >> 3, cc = c & 7;
      int ccs = cc ^ (row & 7);
      async_cp16(Ae + (size_t)row * DM + kb + ccs * 16, As + c * 16);
      async_cp16(Be + (size_t)row * DM + kb + ccs * 16, Bs + c * 16);
    }
    __syncthreads();
    intx8 af[4], bf[4];
#pragma unroll
    for (int i = 0; i < 4; i++) {
      int row = wm + i * 16 + l15;
      int sw = row & 7;
      int4 lo = *(const int4*)&As[row * 128 + ((2 * q) ^ sw) * 16];
      int4 hi = *(const int4*)&As[row * 128 + ((2 * q + 1) ^ sw) * 16];
      af[i] = (intx8){lo.x, lo.y, lo.z, lo.w, hi.x, hi.y, hi.z, hi.w};
    }
#pragma unroll
    for (int j = 0; j < 4; j++) {
      int row = wn + j * 16 + l15;
      int sw = row & 7;
      int4 lo = *(const int4*)&Bs[row * 128 + ((2 * q) ^ sw) * 16];
      int4 hi = *(const int4*)&Bs[row * 128 + ((2 * q + 1) ^ sw) * 16];
      bf[j] = (intx8){lo.x, lo.y, lo.z, lo.w, hi.x, hi.y, hi.z, hi.w};
    }
#pragma unroll
    for (int i = 0; i < 4; i++)
#pragma unroll
      for (int j = 0; j < 4; j++)
        acc[i][j] = __builtin_amdgcn_mfma_scale_f32_16x16x128_f8f6f4(
            bf[j], af[i], acc[i][j], 0, 0, 0, SCALE_W, 0, SCALE_ONE);
    __syncthreads();
  }
  // operand-swap => D: m = l15, n = q*4 + reg
  const float* b1e = b1 + e * DF;
#pragma unroll
  for (int i = 0; i < 4; i++) {
    int m = m0 + wm + i * 16 + l15;
    unsigned char* hrow = H + ((size_t)e * CAP + m) * DF;
#pragma unroll
    for (int j = 0; j < 4; j++) {
      int nb = n0 + wn + j * 16 + q * 4;
      float4 bv = *(const float4*)&b1e[nb];
      floatx4 a = acc[i][j];
      *(int*)&hrow[nb] = pk4(fmaxf(a[0] + bv.x, 0.f), fmaxf(a[1] + bv.y, 0.f),
                             fmaxf(a[2] + bv.z, 0.f), fmaxf(a[3] + bv.w, 0.f));
    }
  }
}

// ---------------------------------------------------------------- GEMM2: out[t] = p*(H @ w2 + b2)
// Hm fp8 [E][CAP][DF], BT=W2T fp8x64 [E][DM][DF]
__global__ void __launch_bounds__(256) gemm2_kernel(
    const unsigned char* __restrict__ Hm, const unsigned char* __restrict__ BT,
    const float* __restrict__ b2, const int* __restrict__ src_token,
    const float* __restrict__ top_prob, float* __restrict__ out) {
  __shared__ unsigned char As[128 * 128];
  __shared__ unsigned char Bs[128 * 128];
  int e = blockIdx.z;
  int n0 = blockIdx.x * 128, m0 = blockIdx.y * 128;
  const unsigned char* Ae = Hm + ((size_t)e * CAP + m0) * DF;
  const unsigned char* Be = BT + ((size_t)e * DM + n0) * DF;
  int tid = threadIdx.x;
  int lane = tid & 63, wid = tid >> 6;
  int wm = (wid & 1) * 64, wn = (wid >> 1) * 64;
  int l15 = lane & 15, q = lane >> 4;
  floatx4 acc[4][4];
#pragma unroll
  for (int i = 0; i < 4; i++)
#pragma unroll
    for (int j = 0; j < 4; j++) acc[i][j] = (floatx4){0.f, 0.f, 0.f, 0.f};
  for (int kb = 0; kb < DF; kb += 128) {
#pragma unroll
    for (int r = 0; r < 4; r++) {
      int c = tid + 256 * r;
      int row = c >> 3, cc = c & 7;
      int ccs = cc ^ (row & 7);
      async_cp16(Ae + (size_t)row * DF + kb + ccs * 16, As + c * 16);
      async_cp16(Be + (size_t)row * DF + kb + ccs * 16, Bs + c * 16);
    }
    __syncthreads();
    intx8 af[4], bf[4];
#pragma unroll
    for (int i = 0; i < 4; i++) {
      int row = wm + i * 16 + l15;
      int sw = row & 7;
      int4 lo = *(const int4*)&As[row * 128 + ((2 * q) ^ sw) * 16];
      int4 hi = *(const int4*)&As[row * 128 + ((2 * q + 1) ^ sw) * 16];
      af[i] = (intx8){lo.x, lo.y, lo.z, lo.w, hi.x, hi.y, hi.z, hi.w};
    }
#pragma unroll
    for (int j = 0; j < 4; j++) {
      int row = wn + j * 16 + l15;
      int sw = row & 7;
      int4 lo = *(const int4*)&Bs[row * 128 + ((2 * q) ^ sw) * 16];
      int4 hi = *(const int4*)&Bs[row * 128 + ((2 * q + 1) ^ sw) * 16];
      bf[j] = (intx8){lo.x, lo.y, lo.z, lo.w, hi.x, hi.y, hi.z, hi.w};
    }
#pragma unroll
    for (int i = 0; i < 4; i++)
#pragma unroll
      for (int j = 0; j < 4; j++)
        acc[i][j] = __builtin_amdgcn_mfma_scale_f32_16x16x128_f8f6f4(
            bf[j], af[i], acc[i][j], 0, 0, 0, SCALE_W, 0, SCALE_ONE);
    __syncthreads();
  }
  const float* b2e = b2 + e * DM;
#pragma unroll
  for (int i = 0; i < 4; i++) {
    int m = m0 + wm + i * 16 + l15;
    int t = src_token[e * CAP + m];
    if (t < 0) continue;
    float p = top_prob[t];
    float* orow = out + (size_t)t * DM;
#pragma unroll
    for (int j = 0; j < 4; j++) {
      int nb = n0 + wn + j * 16 + q * 4;
      float4 bv = *(const float4*)&b2e[nb];
      floatx4 a = acc[i][j];
      float4 o;
      o.x = p * (a[0] + bv.x);
      o.y = p * (a[1] + bv.y);
      o.z = p * (a[2] + bv.z);
      o.w = p * (a[3] + bv.w);
      *(float4*)&orow[nb] = o;
    }
  }
}

// ---------------------------------------------------------------- dropped-token passthrough
__global__ void __launch_bounds__(256) passthru_kernel(
    const float* __restrict__ x, const int* __restrict__ dest_slot,
    float* __restrict__ out) {
  int t = blockIdx.x;
  if (dest_slot[t] >= 0) return;
  int c = threadIdx.x * 4;
  *(float4*)&out[(size_t)t * DM + c] = *(const float4*)&x[(size_t)t * DM + c];
}

// ---------------------------------------------------------------- launch
extern "C" void kernel_launch(void* const* d_in, const int* in_sizes, int n_in,
                              void* d_out, int out_size, void* d_ws, size_t ws_size,
                              hipStream_t stream) {
  const float* x  = (const float*)d_in[0];
  const float* wr = (const float*)d_in[1];
  const float* w1 = (const float*)d_in[2];
  const float* b1 = (const float*)d_in[3];
  const float* w2 = (const float*)d_in[4];
  const float* b2 = (const float*)d_in[5];
  float* out = (float*)d_out;

  // workspace layout (bytes)
  const size_t OFF_A    = 0;             // 16,777,216  A fp8 [E*CAP][DM]
  const size_t OFF_W1T  = 16777216;      // 33,554,432  W1T fp8 [E][DF][DM]
  const size_t OFF_W2T  = 50331648;      // 33,554,432  W2T fp8 [E][DM][DF]
  const size_t OFF_H    = 83886080;      // 67,108,864  H fp8 [E][CAP][DF]
  const size_t OFF_TIDX = 150994944;
  const size_t OFF_TPRB = 151060480;
  const size_t OFF_DEST = 151126016;
  const size_t OFF_SRC  = 151191552;
  const size_t OFF_STAT = 151257088;
  if (ws_size < OFF_STAT + 64) return;

  char* ws = (char*)d_ws;
  unsigned char* A_f8 = (unsigned char*)(ws + OFF_A);
  unsigned char* W1T  = (unsigned char*)(ws + OFF_W1T);
  unsigned char* W2T  = (unsigned char*)(ws + OFF_W2T);
  unsigned char* Hbuf = (unsigned char*)(ws + OFF_H);
  int*   top_idx   = (int*)(ws + OFF_TIDX);
  float* top_prob  = (float*)(ws + OFF_TPRB);
  int*   dest_slot = (int*)(ws + OFF_DEST);
  int*   src_token = (int*)(ws + OFF_SRC);
  float* stats     = (float*)(ws + OFF_STAT);

  hipLaunchKernelGGL(init_kernel, dim3(64), dim3(256), 0, stream, src_token, stats);
  hipLaunchKernelGGL(router_kernel, dim3(512), dim3(256), 0, stream,
                     x, wr, top_idx, top_prob, stats);
  hipLaunchKernelGGL(scan_kernel, dim3(1), dim3(1024), 0, stream,
                     top_idx, stats, dest_slot, src_token, out + (size_t)T_TOK * DM);
  hipLaunchKernelGGL(dispatch_kernel, dim3(NE * CAP), dim3(256), 0, stream,
                     x, src_token, A_f8);
  hipLaunchKernelGGL(transpose_cast_kernel, dim3(DF / 64, DM / 64, NE), dim3(256), 0, stream,
                     w1, W1T, DM, DF);
  hipLaunchKernelGGL(transpose_cast_kernel, dim3(DM / 64, DF / 64, NE), dim3(256), 0, stream,
                     w2, W2T, DF, DM);
  hipLaunchKernelGGL(gemm1_kernel, dim3(DF / 128, CAP / 128, NE), dim3(256), 0, stream,
                     A_f8, W1T, b1, Hbuf);
  hipLaunchKernelGGL(gemm2_kernel, dim3(DM / 128, CAP / 128, NE), dim3(256), 0, stream,
                     Hbuf, W2T, b2, src_token, top_prob, out);
  hipLaunchKernelGGL(passthru_kernel, dim3(T_TOK), dim3(256), 0, stream,
                     x, dest_slot, out);
}